// Round 1
// baseline (4916.481 us; speedup 1.0000x reference)
//
#include <hip/hip_runtime.h>
#include <math.h>

#define TDIM 256
#define CCH  128      // channels
#define HW   32       // height == width
#define OCT  8        // out channels per block
#define ICT  4        // in channels staged per barrier
#define RPB  16       // output rows per block
#define SW   37       // LDS tile row stride (36 valid + 1 pad, odd to spread banks)
#define SROWS (RPB + 4)

// EPI 0: integrate (conv(spike)*sigmoid gate -> mem_post)
// EPI 1: fire      (conv(mem_post) -> sign gate; threshold/reset; emit spikes)
template<int EPI>
__global__ __launch_bounds__(TDIM) void lif_conv(
    const float* __restrict__ cin,   // conv input plane set [B,C,32,32]
    const float* __restrict__ wgt,   // [C,C,5,5] OIHW
    const float* __restrict__ bias,  // [C]
    const float* __restrict__ aux0,  // EPI0: mem_cur ; EPI1: mem_post
    const float* __restrict__ aux1,  // EPI0: x_t     ; EPI1: unused
    float* __restrict__ out0,        // EPI0: mem_post; EPI1: mem_next
    float* __restrict__ out1,        // EPI1: spikes out[t]
    int first)
{
    const int ocg  = blockIdx.x;          // 0..15
    const int half = blockIdx.y;          // 0..1
    const int b    = blockIdx.z;          // 0..15
    const int oc0  = ocg * OCT;
    const int r0   = half * RPB;
    const int tid  = threadIdx.x;

    __shared__ float s_in[ICT][SROWS * SW];
    __shared__ float s_w[OCT][ICT][25];

    float acc[OCT][2];
#pragma unroll
    for (int oc = 0; oc < OCT; ++oc) { acc[oc][0] = 0.f; acc[oc][1] = 0.f; }

    const int rl = tid >> 4;          // 0..15  output row within block
    const int cb = (tid & 15) * 2;    // 0,2,...,30 column pair base

    if (!(EPI == 0 && first)) {
        for (int ic0 = 0; ic0 < CCH; ic0 += ICT) {
            // ---- stage ICT input planes with 2-halo (zeros outside) ----
            for (int idx = tid; idx < ICT * SROWS * SW; idx += TDIM) {
                int ici = idx / (SROWS * SW);
                int rem = idx - ici * (SROWS * SW);
                int lr  = rem / SW;
                int lc  = rem - lr * SW;
                int gr  = r0 + lr - 2;
                int gc  = lc - 2;
                float v = 0.f;
                if (lc < 36 && gr >= 0 && gr < HW && gc >= 0 && gc < HW)
                    v = cin[(((size_t)b * CCH + ic0 + ici) * HW + gr) * HW + gc];
                s_in[ici][lr * SW + lc] = v;
            }
            // ---- stage weights: OCT x ICT x 25 ----
            for (int idx = tid; idx < OCT * ICT * 25; idx += TDIM) {
                int oc  = idx / (ICT * 25);
                int rem = idx - oc * (ICT * 25);
                int ici = rem / 25;
                int k   = rem - ici * 25;
                s_w[oc][ici][k] = wgt[(((size_t)(oc0 + oc)) * CCH + ic0 + ici) * 25 + k];
            }
            __syncthreads();

#pragma unroll
            for (int ici = 0; ici < ICT; ++ici) {
                float win[5][6];
#pragma unroll
                for (int dr = 0; dr < 5; ++dr)
#pragma unroll
                    for (int dc = 0; dc < 6; ++dc)
                        win[dr][dc] = s_in[ici][(rl + dr) * SW + cb + dc];
#pragma unroll
                for (int oc = 0; oc < OCT; ++oc) {
#pragma unroll
                    for (int kh = 0; kh < 5; ++kh)
#pragma unroll
                        for (int kw = 0; kw < 5; ++kw) {
                            float wt = s_w[oc][ici][kh * 5 + kw];
                            acc[oc][0] += win[kh][kw]     * wt;
                            acc[oc][1] += win[kh][kw + 1] * wt;
                        }
                }
            }
            __syncthreads();
        }
    }

    // ---- epilogue: fused LIF pointwise math ----
    const int r = r0 + rl;
#pragma unroll
    for (int oc = 0; oc < OCT; ++oc) {
        const int pidx = (((b * CCH + oc0 + oc) * HW) + r) * HW + cb; // even -> float2 ok
        const float bia = bias[oc0 + oc];
        float y0 = acc[oc][0] + bia;
        float y1 = acc[oc][1] + bia;
        if (EPI == 0) {
            float2 xv = *(const float2*)(aux1 + pidx);
            float2 mv;
            if (first) { mv.x = 0.f; mv.y = 0.f; }
            else        mv = *(const float2*)(aux0 + pidx);
            float g0 = 1.f / (1.f + expf(-y0));
            float g1 = 1.f / (1.f + expf(-y1));
            float2 mp;
            mp.x = 0.2f * mv.x + g0 * xv.x;
            mp.y = 0.2f * mv.y + g1 * xv.y;
            *(float2*)(out0 + pidx) = mp;
        } else {
            float2 m2 = *(const float2*)(aux0 + pidx);
            float g0 = (y0 > 0.f) ? 1.f : ((y0 < 0.f) ? -1.f : 0.f);
            float g1 = (y1 > 0.f) ? 1.f : ((y1 < 0.f) ? -1.f : 0.f);
            float s0 = (m2.x > 0.5f) ? 1.f : 0.f;
            float s1 = (m2.y > 0.5f) ? 1.f : 0.f;
            float2 mn; mn.x = m2.x * (1.f - s0); mn.y = m2.y * (1.f - s1);
            float2 sp; sp.x = g0 * s0;           sp.y = g1 * s1;
            *(float2*)(out0 + pidx) = mn;
            *(float2*)(out1 + pidx) = sp;
        }
    }
}

extern "C" void kernel_launch(void* const* d_in, const int* in_sizes, int n_in,
                              void* d_out, int out_size, void* d_ws, size_t ws_size,
                              hipStream_t stream) {
    const float* x      = (const float*)d_in[0];  // [8,16,128,32,32]
    const float* back_w = (const float*)d_in[1];  // [128,128,5,5]
    const float* back_b = (const float*)d_in[2];  // [128]
    const float* ei_w   = (const float*)d_in[3];
    const float* ei_b   = (const float*)d_in[4];
    float* out = (float*)d_out;                   // [8,16,128,32,32] spikes

    const size_t N = (size_t)16 * CCH * HW * HW;  // 2,097,152 per timestep state
    float* mem_cur  = (float*)d_ws;               // ping-pong membrane (reset)
    float* mem_post = mem_cur + N;                // post-integrate membrane

    dim3 grid(CCH / OCT, HW / RPB, 16);           // (16, 2, 16)

    for (int t = 0; t < 8; ++t) {
        const float* spike_prev = (t == 0) ? x : (out + (size_t)(t - 1) * N);
        // integrate: mem_post = 0.2*mem + sigmoid(conv(spike_prev, back_w)+b) * x[t]
        lif_conv<0><<<grid, TDIM, 0, stream>>>(
            spike_prev, back_w, back_b,
            mem_cur, x + (size_t)t * N,
            mem_post, nullptr, (t == 0) ? 1 : 0);
        // fire: ei = sign(conv(mem_post, ei_w)+b); s = mem_post>0.5;
        //       mem_cur = mem_post*(1-s); out[t] = ei*s
        lif_conv<1><<<grid, TDIM, 0, stream>>>(
            mem_post, ei_w, ei_b,
            mem_post, nullptr,
            mem_cur, out + (size_t)t * N, 0);
    }
}

// Round 2
// 2596.525 us; speedup vs baseline: 1.8935x; 1.8935x over previous
//
#include <hip/hip_runtime.h>
#include <math.h>

#define TDIM 256
#define CCH  128      // channels
#define HW   32       // height == width
#define OCT  4        // out channels per block
#define ICT  8        // in channels staged per barrier
#define SW   40       // LDS tile row stride (36 valid + 4 pad, mult of 4 for b128)
#define SROWS 36
#define PLANE (SROWS * SW)   // 1440 floats per staged plane

// EPI 0: integrate (conv(spike)*sigmoid gate -> mem_post)
// EPI 1: fire      (conv(mem_post) -> sign gate; threshold/reset; emit spikes)
template<int EPI>
__global__ __launch_bounds__(TDIM, 2) void lif_conv(
    const float* __restrict__ cin,   // conv input [B,C,32,32]
    const float* __restrict__ wgt,   // [C,C,5,5] OIHW
    const float* __restrict__ bias,  // [C]
    const float* __restrict__ aux0,  // EPI0: mem_cur ; EPI1: mem_post
    const float* __restrict__ aux1,  // EPI0: x_t     ; EPI1: unused
    float* __restrict__ out0,        // EPI0: mem_post; EPI1: mem_next
    float* __restrict__ out1,        // EPI1: spikes out[t]
    int first)
{
    const int ocg = blockIdx.x;          // 0..31
    const int b   = blockIdx.y;          // 0..15
    const int oc0 = ocg * OCT;
    const int tid = threadIdx.x;
    const int rl  = tid >> 3;            // 0..31 output row
    const int cl  = (tid & 7) * 4;       // 0,4,...,28 column base (4 px/thread)

    __shared__ __align__(16) float s_in[ICT * PLANE];   // 46080 B

    float acc[OCT][4];
#pragma unroll
    for (int oc = 0; oc < OCT; ++oc)
#pragma unroll
        for (int j = 0; j < 4; ++j) acc[oc][j] = 0.f;

    if (!(EPI == 0 && first)) {
        // zero whole tile once: pad rows/cols stay zero across all phases
        for (int i = tid; i < ICT * PLANE; i += TDIM) s_in[i] = 0.f;

        for (int ic0 = 0; ic0 < CCH; ic0 += ICT) {
            __syncthreads();   // protect prev-phase reads (and initial zeroing)
            // ---- stage ICT interior planes, float4 loads, float2 LDS writes ----
#pragma unroll
            for (int it = 0; it < (ICT * HW * 8) / TDIM; ++it) {   // 8 iters
                int idx = tid + it * TDIM;
                int p   = idx >> 8;          // plane 0..7
                int rem = idx & 255;
                int gr  = rem >> 3;          // global row 0..31
                int g   = rem & 7;           // col group (4 floats)
                float4 v = *(const float4*)&cin[(((size_t)b * CCH + ic0 + p) * HW + gr) * HW + g * 4];
                float* dst = &s_in[p * PLANE + (gr + 2) * SW + 2 + g * 4];
                *(float2*)dst       = make_float2(v.x, v.y);
                *(float2*)(dst + 2) = make_float2(v.z, v.w);
            }
            __syncthreads();
            // ---- compute: weights via uniform (scalar) loads, windows via b128 ----
#pragma unroll
            for (int ici = 0; ici < ICT; ++ici) {
                const float* wb = wgt + ((size_t)oc0 * CCH + (ic0 + ici)) * 25;
#pragma unroll
                for (int kh = 0; kh < 5; ++kh) {
                    const float* src = &s_in[ici * PLANE + (rl + kh) * SW + cl];
                    float4 w0 = *(const float4*)src;
                    float4 w1 = *(const float4*)(src + 4);
                    float win[8] = {w0.x, w0.y, w0.z, w0.w, w1.x, w1.y, w1.z, w1.w};
#pragma unroll
                    for (int oc = 0; oc < OCT; ++oc) {
#pragma unroll
                        for (int kw = 0; kw < 5; ++kw) {
                            float wv = wb[oc * (CCH * 25) + kh * 5 + kw];  // wave-uniform -> s_load
                            acc[oc][0] += win[kw]     * wv;
                            acc[oc][1] += win[kw + 1] * wv;
                            acc[oc][2] += win[kw + 2] * wv;
                            acc[oc][3] += win[kw + 3] * wv;
                        }
                    }
                }
            }
        }
    }

    // ---- epilogue: fused LIF pointwise math, float4 I/O ----
#pragma unroll
    for (int oc = 0; oc < OCT; ++oc) {
        const size_t pidx = (((size_t)b * CCH + oc0 + oc) * HW + rl) * HW + cl;
        const float bia = bias[oc0 + oc];
        float y[4];
#pragma unroll
        for (int j = 0; j < 4; ++j) y[j] = acc[oc][j] + bia;
        if (EPI == 0) {
            float4 xv = *(const float4*)(aux1 + pidx);
            float4 mv;
            if (first) { mv.x = mv.y = mv.z = mv.w = 0.f; }
            else       mv = *(const float4*)(aux0 + pidx);
            float4 mp;
            mp.x = 0.2f * mv.x + (1.f / (1.f + expf(-y[0]))) * xv.x;
            mp.y = 0.2f * mv.y + (1.f / (1.f + expf(-y[1]))) * xv.y;
            mp.z = 0.2f * mv.z + (1.f / (1.f + expf(-y[2]))) * xv.z;
            mp.w = 0.2f * mv.w + (1.f / (1.f + expf(-y[3]))) * xv.w;
            *(float4*)(out0 + pidx) = mp;
        } else {
            float4 m4 = *(const float4*)(aux0 + pidx);
            float g[4] = {
                (y[0] > 0.f) ? 1.f : ((y[0] < 0.f) ? -1.f : 0.f),
                (y[1] > 0.f) ? 1.f : ((y[1] < 0.f) ? -1.f : 0.f),
                (y[2] > 0.f) ? 1.f : ((y[2] < 0.f) ? -1.f : 0.f),
                (y[3] > 0.f) ? 1.f : ((y[3] < 0.f) ? -1.f : 0.f)};
            float m[4] = {m4.x, m4.y, m4.z, m4.w};
            float4 mn, sp;
            float s0 = (m[0] > 0.5f) ? 1.f : 0.f;
            float s1 = (m[1] > 0.5f) ? 1.f : 0.f;
            float s2 = (m[2] > 0.5f) ? 1.f : 0.f;
            float s3 = (m[3] > 0.5f) ? 1.f : 0.f;
            mn.x = m[0] * (1.f - s0); sp.x = g[0] * s0;
            mn.y = m[1] * (1.f - s1); sp.y = g[1] * s1;
            mn.z = m[2] * (1.f - s2); sp.z = g[2] * s2;
            mn.w = m[3] * (1.f - s3); sp.w = g[3] * s3;
            *(float4*)(out0 + pidx) = mn;
            *(float4*)(out1 + pidx) = sp;
        }
    }
}

extern "C" void kernel_launch(void* const* d_in, const int* in_sizes, int n_in,
                              void* d_out, int out_size, void* d_ws, size_t ws_size,
                              hipStream_t stream) {
    const float* x      = (const float*)d_in[0];  // [8,16,128,32,32]
    const float* back_w = (const float*)d_in[1];  // [128,128,5,5]
    const float* back_b = (const float*)d_in[2];  // [128]
    const float* ei_w   = (const float*)d_in[3];
    const float* ei_b   = (const float*)d_in[4];
    float* out = (float*)d_out;                   // [8,16,128,32,32] spikes

    const size_t N = (size_t)16 * CCH * HW * HW;  // per-timestep state elements
    float* mem_cur  = (float*)d_ws;               // ping-pong membrane (reset)
    float* mem_post = mem_cur + N;                // post-integrate membrane

    dim3 grid(CCH / OCT, 16);                     // (32, 16) = 512 blocks

    for (int t = 0; t < 8; ++t) {
        const float* spike_prev = (t == 0) ? x : (out + (size_t)(t - 1) * N);
        // integrate: mem_post = 0.2*mem + sigmoid(conv(spike_prev, back_w)+b) * x[t]
        lif_conv<0><<<grid, TDIM, 0, stream>>>(
            spike_prev, back_w, back_b,
            mem_cur, x + (size_t)t * N,
            mem_post, nullptr, (t == 0) ? 1 : 0);
        // fire: ei = sign(conv(mem_post, ei_w)+b); s = mem_post>0.5;
        //       mem_cur = mem_post*(1-s); out[t] = ei*s
        lif_conv<1><<<grid, TDIM, 0, stream>>>(
            mem_post, ei_w, ei_b,
            mem_post, nullptr,
            mem_cur, out + (size_t)t * N, 0);
    }
}